// Round 21
// baseline (212.685 us; speedup 1.0000x reference)
//
#include <hip/hip_runtime.h>

#define DIM 128
#define NEG_SLOPE 0.01f
#define ELLW 64
#define CPAD 16  // one cursor per 64B line
#define LDA 136
#define SPLIT 4  // blocks per graph in k_gp
#define WPAD 132 // per-wave row in reduce scratch

typedef short short8 __attribute__((ext_vector_type(8)));
typedef unsigned short ushort8 __attribute__((ext_vector_type(8)));
typedef float f32x4 __attribute__((ext_vector_type(4)));

__device__ __forceinline__ unsigned short f2bf(float f) {
    unsigned u = __float_as_uint(f);
    u = u + 0x7FFFu + ((u >> 16) & 1u);
    return (unsigned short)(u >> 16);
}
__device__ __forceinline__ float bf2f(unsigned short s) {
    return __uint_as_float((unsigned)s << 16);
}

// ---- fused: ELL fill (ushort src, 2 edges/thread) + W prep + gOff ---------------
__global__ __launch_bounds__(256) void k_fillprep(const int* __restrict__ src,
                                                  const int* __restrict__ dst,
                                                  const int* __restrict__ batch,
                                                  int* __restrict__ cursorPad,
                                                  unsigned short* __restrict__ eSrc,
                                                  const float* __restrict__ W1,
                                                  const float* __restrict__ W2,
                                                  unsigned short* __restrict__ Wt1,
                                                  unsigned short* __restrict__ Wt2,
                                                  int* __restrict__ gOff,
                                                  int nE, int nN, int nG) {
    int i = blockIdx.x * 256 + threadIdx.x;
    const int half = (nE + 1) >> 1;
    // two independent edge chains per thread
    if (i < half) {
        int s = src[i], d = dst[i];
        int pos = atomicAdd(&cursorPad[d * CPAD], 1);
        if (pos < ELLW) eSrc[(size_t)d * ELLW + pos] = (unsigned short)s;
    }
    int i2 = i + half;
    if (i2 < nE) {
        int s = src[i2], d = dst[i2];
        int pos = atomicAdd(&cursorPad[d * CPAD], 1);
        if (pos < ELLW) eSrc[(size_t)d * ELLW + pos] = (unsigned short)s;
    }
    if (i < nN) {
        int b1 = batch[i];
        int b0 = (i == 0) ? -1 : batch[i - 1];
        for (int g = b0 + 1; g <= b1; ++g) gOff[g] = i;
        if (i == nN - 1) {
            for (int g = b1 + 1; g <= nG; ++g) gOff[g] = nN;
        }
    }
    if (i < 32768) {
        const float* W = (i < 16384) ? W1 : W2;
        unsigned short* Wt = (i < 16384) ? Wt1 : Wt2;
        int j = i & 16383;
        int k = j >> 7, n = j & 127;
        Wt[n * 128 + k] = f2bf(W[k * 128 + n]);
    }
}

// ---------------- MFMA GEMM: Y_bf16 = (X_f32 @ W) * dinv[row] (layer 1) ----------
__global__ __launch_bounds__(256) void k_gemm(const float* __restrict__ X,
                                              const unsigned short* __restrict__ Wt,
                                              const int* __restrict__ cursorPad,
                                              unsigned short* __restrict__ Y, int nRows) {
    __shared__ unsigned short sA[64 * LDA];   // 17.4 KB
    const int t = threadIdx.x;
    const int row0 = blockIdx.x * 64;

#pragma unroll
    for (int rep = 0; rep < 8; ++rep) {
        int idx = t + rep * 256;
        int r = idx >> 5, k4 = (idx & 31) * 4;
        int gr = row0 + r;
        float4 v = make_float4(0.f, 0.f, 0.f, 0.f);
        if (gr < nRows) v = *(const float4*)&X[(size_t)gr * 128 + k4];
        ushort4 p;
        p.x = f2bf(v.x); p.y = f2bf(v.y); p.z = f2bf(v.z); p.w = f2bf(v.w);
        *(ushort4*)&sA[r * LDA + k4] = p;
    }
    __syncthreads();

    const int wave = t >> 6, lane = t & 63;
    const int l15 = lane & 15;
    const int koff = (lane >> 4) * 8;
    const int arow = wave * 16 + l15;

    short8 a[4];
#pragma unroll
    for (int ks = 0; ks < 4; ++ks)
        a[ks] = *(const short8*)&sA[arow * LDA + ks * 32 + koff];

    f32x4 acc[8];
#pragma unroll
    for (int c = 0; c < 8; ++c) acc[c] = (f32x4){0.f, 0.f, 0.f, 0.f};
#pragma unroll
    for (int c = 0; c < 8; ++c) {
        const unsigned short* wp = Wt + (size_t)(c * 16 + l15) * 128 + koff;
#pragma unroll
        for (int ks = 0; ks < 4; ++ks) {
            short8 b = *(const short8*)(wp + ks * 32);
            acc[c] = __builtin_amdgcn_mfma_f32_16x16x32_bf16(a[ks], b, acc[c], 0, 0, 0);
        }
    }
    const int orow = row0 + wave * 16 + (lane >> 4) * 4;
#pragma unroll
    for (int r = 0; r < 4; ++r) {
        int gr = orow + r;
        if (gr < nRows) {
            float dv = rsqrtf((float)cursorPad[gr * CPAD] + 1.0f);
#pragma unroll
            for (int c = 0; c < 8; ++c)
                Y[(size_t)gr * 128 + c * 16 + l15] = f2bf(acc[c][r] * dv);
        }
    }
}

// acc += v (8 bf16); rows pre-scaled by dinv in GEMM epilogue
#define ACCUM(v)                                         \
    do {                                                 \
        acc[0] += bf2f((v).x & 0xFFFFu);                 \
        acc[1] += __uint_as_float((v).x & 0xFFFF0000u);  \
        acc[2] += bf2f((v).y & 0xFFFFu);                 \
        acc[3] += __uint_as_float((v).y & 0xFFFF0000u);  \
        acc[4] += bf2f((v).z & 0xFFFFu);                 \
        acc[5] += __uint_as_float((v).z & 0xFFFF0000u);  \
        acc[6] += bf2f((v).w & 0xFFFFu);                 \
        acc[7] += __uint_as_float((v).w & 0xFFFF0000u);  \
    } while (0)

// gather one node (16 lanes; lane l -> cols l*8..l*8+7); h pre-scaled by dinv.
// acc = relu( di * (h'_i + sum_s h'_s) + bias )
__device__ __forceinline__ void gather_body(const uint4* __restrict__ h4,
                                            const int* __restrict__ cursorPad,
                                            const unsigned short* __restrict__ eSrc,
                                            const float* __restrict__ bias,
                                            int i, int l, float* acc) {
    const int beg = i * ELLW;
    const int cnt = cursorPad[i * CPAD];
    const int deg = min(cnt, ELLW);
    const int end = beg + deg;
    const float di = rsqrtf((float)cnt + 1.0f);

    {
        uint4 hv = h4[(size_t)i * 16 + l];
        acc[0] = bf2f(hv.x & 0xFFFFu);
        acc[1] = __uint_as_float(hv.x & 0xFFFF0000u);
        acc[2] = bf2f(hv.y & 0xFFFFu);
        acc[3] = __uint_as_float(hv.y & 0xFFFF0000u);
        acc[4] = bf2f(hv.z & 0xFFFFu);
        acc[5] = __uint_as_float(hv.z & 0xFFFF0000u);
        acc[6] = bf2f(hv.w & 0xFFFFu);
        acc[7] = __uint_as_float(hv.w & 0xFFFF0000u);
    }
    int e = beg;
    for (; e + 8 <= end; e += 8) {
        ushort8 s = *(const ushort8*)&eSrc[e];   // one 16B meta load
        uint4 v[8];
        v[0] = h4[(size_t)s[0] * 16 + l];
        v[1] = h4[(size_t)s[1] * 16 + l];
        v[2] = h4[(size_t)s[2] * 16 + l];
        v[3] = h4[(size_t)s[3] * 16 + l];
        v[4] = h4[(size_t)s[4] * 16 + l];
        v[5] = h4[(size_t)s[5] * 16 + l];
        v[6] = h4[(size_t)s[6] * 16 + l];
        v[7] = h4[(size_t)s[7] * 16 + l];
#pragma unroll
        for (int j = 0; j < 8; ++j) ACCUM(v[j]);
    }
    if (e + 4 <= end) {
        ushort4 s = *(const ushort4*)&eSrc[e];
        uint4 v[4];
        v[0] = h4[(size_t)s.x * 16 + l];
        v[1] = h4[(size_t)s.y * 16 + l];
        v[2] = h4[(size_t)s.z * 16 + l];
        v[3] = h4[(size_t)s.w * 16 + l];
#pragma unroll
        for (int j = 0; j < 4; ++j) ACCUM(v[j]);
        e += 4;
    }
    if (e + 2 <= end) {
        int s0 = eSrc[e], s1 = eSrc[e + 1];
        uint4 v0 = h4[(size_t)s0 * 16 + l];
        uint4 v1 = h4[(size_t)s1 * 16 + l];
        ACCUM(v0);
        ACCUM(v1);
        e += 2;
    }
    if (e < end) {
        int s0 = eSrc[e];
        uint4 v0 = h4[(size_t)s0 * 16 + l];
        ACCUM(v0);
    }

    float4 b0 = *(const float4*)&bias[l * 8];
    float4 b1 = *(const float4*)&bias[l * 8 + 4];
    acc[0] = acc[0] * di + b0.x; acc[0] = acc[0] > 0.f ? acc[0] : NEG_SLOPE * acc[0];
    acc[1] = acc[1] * di + b0.y; acc[1] = acc[1] > 0.f ? acc[1] : NEG_SLOPE * acc[1];
    acc[2] = acc[2] * di + b0.z; acc[2] = acc[2] > 0.f ? acc[2] : NEG_SLOPE * acc[2];
    acc[3] = acc[3] * di + b0.w; acc[3] = acc[3] > 0.f ? acc[3] : NEG_SLOPE * acc[3];
    acc[4] = acc[4] * di + b1.x; acc[4] = acc[4] > 0.f ? acc[4] : NEG_SLOPE * acc[4];
    acc[5] = acc[5] * di + b1.y; acc[5] = acc[5] > 0.f ? acc[5] : NEG_SLOPE * acc[5];
    acc[6] = acc[6] * di + b1.z; acc[6] = acc[6] > 0.f ? acc[6] : NEG_SLOPE * acc[6];
    acc[7] = acc[7] * di + b1.w; acc[7] = acc[7] > 0.f ? acc[7] : NEG_SLOPE * acc[7];
}
#undef ACCUM

// ---- fused gather1 -> LDS 16-row A-tile -> MFMA @ W2 * dinv -> Y ----------------
__global__ __launch_bounds__(256) void k_gg(const uint4* __restrict__ h4in,
                                            const int* __restrict__ cursorPad,
                                            const unsigned short* __restrict__ eSrc,
                                            const float* __restrict__ bias,
                                            const unsigned short* __restrict__ Wt,
                                            unsigned short* __restrict__ Y, int nN) {
    __shared__ unsigned short sA[16 * LDA];  // 4.3 KB
    const int t = threadIdx.x;
    const int row0 = blockIdx.x * 16;
    const int lg = t >> 4;
    const int l = t & 15;

    {
        int i = row0 + lg;
        float acc[8];
        if (i < nN) {
            gather_body(h4in, cursorPad, eSrc, bias, i, l, acc);
        } else {
#pragma unroll
            for (int j = 0; j < 8; ++j) acc[j] = 0.0f;
        }
        ushort4 p0, p1;
        p0.x = f2bf(acc[0]); p0.y = f2bf(acc[1]); p0.z = f2bf(acc[2]); p0.w = f2bf(acc[3]);
        p1.x = f2bf(acc[4]); p1.y = f2bf(acc[5]); p1.z = f2bf(acc[6]); p1.w = f2bf(acc[7]);
        *(ushort4*)&sA[lg * LDA + l * 8] = p0;
        *(ushort4*)&sA[lg * LDA + l * 8 + 4] = p1;
    }
    __syncthreads();

    const int wave = t >> 6, lane = t & 63;
    const int l15 = lane & 15;
    const int koff = (lane >> 4) * 8;

    short8 a[4];
#pragma unroll
    for (int ks = 0; ks < 4; ++ks)
        a[ks] = *(const short8*)&sA[l15 * LDA + ks * 32 + koff];

    f32x4 acc[2];
#pragma unroll
    for (int cb = 0; cb < 2; ++cb) acc[cb] = (f32x4){0.f, 0.f, 0.f, 0.f};
#pragma unroll
    for (int cb = 0; cb < 2; ++cb) {
        const int c = wave * 2 + cb;
        const unsigned short* wp = Wt + (size_t)(c * 16 + l15) * 128 + koff;
#pragma unroll
        for (int ks = 0; ks < 4; ++ks) {
            short8 b = *(const short8*)(wp + ks * 32);
            acc[cb] = __builtin_amdgcn_mfma_f32_16x16x32_bf16(a[ks], b, acc[cb], 0, 0, 0);
        }
    }
    const int orow = row0 + (lane >> 4) * 4;
#pragma unroll
    for (int r = 0; r < 4; ++r) {
        int gr = orow + r;
        if (gr < nN) {
            float dv = rsqrtf((float)cursorPad[gr * CPAD] + 1.0f);
#pragma unroll
            for (int cb = 0; cb < 2; ++cb)
                Y[(size_t)gr * 128 + (wave * 2 + cb) * 16 + l15] = f2bf(acc[cb][r] * dv);
        }
    }
}

// ---- fused gather2 + mean pool: SPLIT blocks per graph, gOff bounds -------------
__global__ __launch_bounds__(256) void k_gp(const uint4* __restrict__ h4in,
                                            const int* __restrict__ cursorPad,
                                            const unsigned short* __restrict__ eSrc,
                                            const float* __restrict__ bias,
                                            const int* __restrict__ gOff,
                                            float* __restrict__ out, int nN, int nG) {
    __shared__ float accW[4 * WPAD];  // 2.1 KB
    const int g = blockIdx.x / SPLIT;
    const int part = blockIdx.x % SPLIT;
    const int t = threadIdx.x;
    const int beg = gOff[g], end = gOff[g + 1];
    const int lg = t >> 4, l = t & 15;
    const int wave = t >> 6, lane = t & 63;

    float acc8[8];
#pragma unroll
    for (int j = 0; j < 8; ++j) acc8[j] = 0.0f;

    for (int base = beg + part * 16; base < end; base += SPLIT * 16) {
        int i = base + lg;
        if (i < end) {
            float a[8];
            gather_body(h4in, cursorPad, eSrc, bias, i, l, a);
#pragma unroll
            for (int j = 0; j < 8; ++j) acc8[j] += a[j];
        }
    }
#pragma unroll
    for (int j = 0; j < 8; ++j) {
        acc8[j] += __shfl_down(acc8[j], 32);
        acc8[j] += __shfl_down(acc8[j], 16);
    }
    if (lane < 16) {
        *(float4*)&accW[wave * WPAD + lane * 8] =
            make_float4(acc8[0], acc8[1], acc8[2], acc8[3]);
        *(float4*)&accW[wave * WPAD + lane * 8 + 4] =
            make_float4(acc8[4], acc8[5], acc8[6], acc8[7]);
    }
    __syncthreads();
    if (t < 128) {
        float s = accW[0 * WPAD + t] + accW[1 * WPAD + t] +
                  accW[2 * WPAD + t] + accW[3 * WPAD + t];
        float cnt = (float)(end - beg);
        atomicAdd(&out[(size_t)g * DIM + t], s / fmaxf(cnt, 1.0f));
    }
}

extern "C" void kernel_launch(void* const* d_in, const int* in_sizes, int n_in,
                              void* d_out, int out_size, void* d_ws, size_t ws_size,
                              hipStream_t stream) {
    const float* X  = (const float*)d_in[0];
    const float* W1 = (const float*)d_in[1];
    const float* b1 = (const float*)d_in[2];
    const float* W2 = (const float*)d_in[3];
    const float* b2 = (const float*)d_in[4];
    const int*   ei = (const int*)d_in[5];
    const int*   batch = (const int*)d_in[6];
    float* out = (float*)d_out;

    const int NN = in_sizes[0] / DIM;     // 50000
    const int NE = in_sizes[5] / 2;       // 600000
    const int NG = out_size / DIM;        // 1000

    const int* src = ei;
    const int* dst = ei + NE;

    char* ws = (char*)d_ws;
    size_t o = 0;
    auto alloc = [&](size_t bytes) {
        char* p = ws + o;
        o += (bytes + 1023) & ~(size_t)1023;
        return p;
    };
    int* cursorPad = (int*)alloc((size_t)NN * CPAD * 4);  // 3.2 MB
    int* gOff      = (int*)alloc((size_t)(NG + 1) * 4);
    unsigned short* Wt1 = (unsigned short*)alloc((size_t)16384 * 2);
    unsigned short* Wt2 = (unsigned short*)alloc((size_t)16384 * 2);
    unsigned short* eSrc = (unsigned short*)alloc((size_t)NN * ELLW * 2);  // 6.4 MB
    unsigned short* bufA = (unsigned short*)alloc((size_t)NN * DIM * 2);   // h1' bf16
    unsigned short* bufB = (unsigned short*)alloc((size_t)NN * DIM * 2);   // h2' bf16

    hipMemsetAsync(cursorPad, 0, (size_t)NN * CPAD * 4, stream);
    hipMemsetAsync(out, 0, (size_t)out_size * 4, stream);

    const int B = 256;
    const int half = (NE + 1) / 2;

    // ---- fused fill (2 edges/thread) + W prep + gOff ----
    k_fillprep<<<(half + B - 1) / B, B, 0, stream>>>(src, dst, batch, cursorPad, eSrc,
                                                     W1, W2, Wt1, Wt2, gOff, NE, NN, NG);

    // ---- layer 1 GEMM: bufA = (X @ W1) * dinv ----
    k_gemm<<<(NN + 63) / 64, B, 0, stream>>>(X, Wt1, cursorPad, bufA, NN);

    // ---- fused gather1 + GEMM2 (16-row tiles) ----
    k_gg<<<(NN + 15) / 16, B, 0, stream>>>((const uint4*)bufA, cursorPad, eSrc, b1,
                                           Wt2, bufB, NN);

    // ---- fused gather2 + mean pool ----
    k_gp<<<NG * SPLIT, B, 0, stream>>>((const uint4*)bufB, cursorPad, eSrc, b2,
                                       gOff, out, NN, NG);
}

// Round 22
// 201.429 us; speedup vs baseline: 1.0559x; 1.0559x over previous
//
#include <hip/hip_runtime.h>

#define DIM 128
#define NEG_SLOPE 0.01f
#define ELLW 64
#define CPAD 16  // one cursor per 64B line
#define LDA 136
#define SPLIT 4  // blocks per graph in k_gp
#define WPAD 132 // per-wave row in reduce scratch

typedef short short8 __attribute__((ext_vector_type(8)));
typedef float f32x4 __attribute__((ext_vector_type(4)));

__device__ __forceinline__ unsigned short f2bf(float f) {
    unsigned u = __float_as_uint(f);
    u = u + 0x7FFFu + ((u >> 16) & 1u);
    return (unsigned short)(u >> 16);
}
__device__ __forceinline__ float bf2f(unsigned short s) {
    return __uint_as_float((unsigned)s << 16);
}

// ---- fused: ELL fill (src only) + W prep + gOff boundary detection --------------
__global__ __launch_bounds__(256) void k_fillprep(const int* __restrict__ src,
                                                  const int* __restrict__ dst,
                                                  const int* __restrict__ batch,
                                                  int* __restrict__ cursorPad,
                                                  int* __restrict__ eSrc,
                                                  const float* __restrict__ W1,
                                                  const float* __restrict__ W2,
                                                  unsigned short* __restrict__ Wt1,
                                                  unsigned short* __restrict__ Wt2,
                                                  int* __restrict__ gOff,
                                                  int nE, int nN, int nG) {
    int i = blockIdx.x * 256 + threadIdx.x;
    if (i < nE) {
        int s = src[i], d = dst[i];
        int pos = atomicAdd(&cursorPad[d * CPAD], 1);
        if (pos < ELLW) eSrc[(size_t)d * ELLW + pos] = s;
    }
    if (i < nN) {
        int b1 = batch[i];
        int b0 = (i == 0) ? -1 : batch[i - 1];
        for (int g = b0 + 1; g <= b1; ++g) gOff[g] = i;
        if (i == nN - 1) {
            for (int g = b1 + 1; g <= nG; ++g) gOff[g] = nN;
        }
    }
    if (i < 32768) {
        const float* W = (i < 16384) ? W1 : W2;
        unsigned short* Wt = (i < 16384) ? Wt1 : Wt2;
        int j = i & 16383;
        int k = j >> 7, n = j & 127;
        Wt[n * 128 + k] = f2bf(W[k * 128 + n]);
    }
}

// ---------------- MFMA GEMM: Y_bf16 = (X_f32 @ W) * dinv[row] (layer 1) ----------
__global__ __launch_bounds__(256) void k_gemm(const float* __restrict__ X,
                                              const unsigned short* __restrict__ Wt,
                                              const int* __restrict__ cursorPad,
                                              unsigned short* __restrict__ Y, int nRows) {
    __shared__ unsigned short sA[64 * LDA];   // 17.4 KB
    const int t = threadIdx.x;
    const int row0 = blockIdx.x * 64;

#pragma unroll
    for (int rep = 0; rep < 8; ++rep) {
        int idx = t + rep * 256;
        int r = idx >> 5, k4 = (idx & 31) * 4;
        int gr = row0 + r;
        float4 v = make_float4(0.f, 0.f, 0.f, 0.f);
        if (gr < nRows) v = *(const float4*)&X[(size_t)gr * 128 + k4];
        ushort4 p;
        p.x = f2bf(v.x); p.y = f2bf(v.y); p.z = f2bf(v.z); p.w = f2bf(v.w);
        *(ushort4*)&sA[r * LDA + k4] = p;
    }
    __syncthreads();

    const int wave = t >> 6, lane = t & 63;
    const int l15 = lane & 15;
    const int koff = (lane >> 4) * 8;
    const int arow = wave * 16 + l15;

    short8 a[4];
#pragma unroll
    for (int ks = 0; ks < 4; ++ks)
        a[ks] = *(const short8*)&sA[arow * LDA + ks * 32 + koff];

    f32x4 acc[8];
#pragma unroll
    for (int c = 0; c < 8; ++c) acc[c] = (f32x4){0.f, 0.f, 0.f, 0.f};
#pragma unroll
    for (int c = 0; c < 8; ++c) {
        const unsigned short* wp = Wt + (size_t)(c * 16 + l15) * 128 + koff;
#pragma unroll
        for (int ks = 0; ks < 4; ++ks) {
            short8 b = *(const short8*)(wp + ks * 32);
            acc[c] = __builtin_amdgcn_mfma_f32_16x16x32_bf16(a[ks], b, acc[c], 0, 0, 0);
        }
    }
    const int orow = row0 + wave * 16 + (lane >> 4) * 4;
#pragma unroll
    for (int r = 0; r < 4; ++r) {
        int gr = orow + r;
        if (gr < nRows) {
            float dv = rsqrtf((float)cursorPad[gr * CPAD] + 1.0f);
#pragma unroll
            for (int c = 0; c < 8; ++c)
                Y[(size_t)gr * 128 + c * 16 + l15] = f2bf(acc[c][r] * dv);
        }
    }
}

// acc += v (8 bf16); rows pre-scaled by dinv in GEMM epilogue
#define ACCUM(v)                                         \
    do {                                                 \
        acc[0] += bf2f((v).x & 0xFFFFu);                 \
        acc[1] += __uint_as_float((v).x & 0xFFFF0000u);  \
        acc[2] += bf2f((v).y & 0xFFFFu);                 \
        acc[3] += __uint_as_float((v).y & 0xFFFF0000u);  \
        acc[4] += bf2f((v).z & 0xFFFFu);                 \
        acc[5] += __uint_as_float((v).z & 0xFFFF0000u);  \
        acc[6] += bf2f((v).w & 0xFFFFu);                 \
        acc[7] += __uint_as_float((v).w & 0xFFFF0000u);  \
    } while (0)

// gather one node (16 lanes; lane l -> cols l*8..l*8+7); h pre-scaled by dinv.
// acc = relu( di * (h'_i + sum_s h'_s) + bias )
__device__ __forceinline__ void gather_body(const uint4* __restrict__ h4,
                                            const int* __restrict__ cursorPad,
                                            const int* __restrict__ eSrc,
                                            const float* __restrict__ bias,
                                            int i, int l, float* acc) {
    const int beg = i * ELLW;
    const int cnt = cursorPad[i * CPAD];
    const int deg = min(cnt, ELLW);
    const int end = beg + deg;
    const float di = rsqrtf((float)cnt + 1.0f);

    {
        uint4 hv = h4[(size_t)i * 16 + l];
        acc[0] = bf2f(hv.x & 0xFFFFu);
        acc[1] = __uint_as_float(hv.x & 0xFFFF0000u);
        acc[2] = bf2f(hv.y & 0xFFFFu);
        acc[3] = __uint_as_float(hv.y & 0xFFFF0000u);
        acc[4] = bf2f(hv.z & 0xFFFFu);
        acc[5] = __uint_as_float(hv.z & 0xFFFF0000u);
        acc[6] = bf2f(hv.w & 0xFFFFu);
        acc[7] = __uint_as_float(hv.w & 0xFFFF0000u);
    }
    int e = beg;
    for (; e + 8 <= end; e += 8) {
        int4 s0 = *(const int4*)&eSrc[e];
        int4 s1 = *(const int4*)&eSrc[e + 4];
        uint4 v[8];
        v[0] = h4[(size_t)s0.x * 16 + l];
        v[1] = h4[(size_t)s0.y * 16 + l];
        v[2] = h4[(size_t)s0.z * 16 + l];
        v[3] = h4[(size_t)s0.w * 16 + l];
        v[4] = h4[(size_t)s1.x * 16 + l];
        v[5] = h4[(size_t)s1.y * 16 + l];
        v[6] = h4[(size_t)s1.z * 16 + l];
        v[7] = h4[(size_t)s1.w * 16 + l];
#pragma unroll
        for (int j = 0; j < 8; ++j) ACCUM(v[j]);
    }
    if (e + 4 <= end) {
        int4 s0 = *(const int4*)&eSrc[e];
        uint4 v[4];
        v[0] = h4[(size_t)s0.x * 16 + l];
        v[1] = h4[(size_t)s0.y * 16 + l];
        v[2] = h4[(size_t)s0.z * 16 + l];
        v[3] = h4[(size_t)s0.w * 16 + l];
#pragma unroll
        for (int j = 0; j < 4; ++j) ACCUM(v[j]);
        e += 4;
    }
    if (e + 2 <= end) {
        int s0 = eSrc[e], s1 = eSrc[e + 1];
        uint4 v0 = h4[(size_t)s0 * 16 + l];
        uint4 v1 = h4[(size_t)s1 * 16 + l];
        ACCUM(v0);
        ACCUM(v1);
        e += 2;
    }
    if (e < end) {
        int s0 = eSrc[e];
        uint4 v0 = h4[(size_t)s0 * 16 + l];
        ACCUM(v0);
    }

    float4 b0 = *(const float4*)&bias[l * 8];
    float4 b1 = *(const float4*)&bias[l * 8 + 4];
    acc[0] = acc[0] * di + b0.x; acc[0] = acc[0] > 0.f ? acc[0] : NEG_SLOPE * acc[0];
    acc[1] = acc[1] * di + b0.y; acc[1] = acc[1] > 0.f ? acc[1] : NEG_SLOPE * acc[1];
    acc[2] = acc[2] * di + b0.z; acc[2] = acc[2] > 0.f ? acc[2] : NEG_SLOPE * acc[2];
    acc[3] = acc[3] * di + b0.w; acc[3] = acc[3] > 0.f ? acc[3] : NEG_SLOPE * acc[3];
    acc[4] = acc[4] * di + b1.x; acc[4] = acc[4] > 0.f ? acc[4] : NEG_SLOPE * acc[4];
    acc[5] = acc[5] * di + b1.y; acc[5] = acc[5] > 0.f ? acc[5] : NEG_SLOPE * acc[5];
    acc[6] = acc[6] * di + b1.z; acc[6] = acc[6] > 0.f ? acc[6] : NEG_SLOPE * acc[6];
    acc[7] = acc[7] * di + b1.w; acc[7] = acc[7] > 0.f ? acc[7] : NEG_SLOPE * acc[7];
}
#undef ACCUM

// ---- fused gather1 -> LDS 16-row A-tile -> MFMA @ W2 * dinv -> Y ----------------
// grid = ceil(nN/16): one gather pass per block (full node-level parallelism);
// 4 waves each compute 2 column-blocks of the 16x128 output.
__global__ __launch_bounds__(256) void k_gg(const uint4* __restrict__ h4in,
                                            const int* __restrict__ cursorPad,
                                            const int* __restrict__ eSrc,
                                            const float* __restrict__ bias,
                                            const unsigned short* __restrict__ Wt,
                                            unsigned short* __restrict__ Y, int nN) {
    __shared__ unsigned short sA[16 * LDA];  // 4.3 KB, holds 16-row h1 tile (bf16)
    const int t = threadIdx.x;
    const int row0 = blockIdx.x * 16;
    const int lg = t >> 4;       // node 0..15
    const int l = t & 15;

    {
        int i = row0 + lg;
        float acc[8];
        if (i < nN) {
            gather_body(h4in, cursorPad, eSrc, bias, i, l, acc);
        } else {
#pragma unroll
            for (int j = 0; j < 8; ++j) acc[j] = 0.0f;
        }
        ushort4 p0, p1;
        p0.x = f2bf(acc[0]); p0.y = f2bf(acc[1]); p0.z = f2bf(acc[2]); p0.w = f2bf(acc[3]);
        p1.x = f2bf(acc[4]); p1.y = f2bf(acc[5]); p1.z = f2bf(acc[6]); p1.w = f2bf(acc[7]);
        *(ushort4*)&sA[lg * LDA + l * 8] = p0;
        *(ushort4*)&sA[lg * LDA + l * 8 + 4] = p1;
    }
    __syncthreads();

    const int wave = t >> 6, lane = t & 63;
    const int l15 = lane & 15;
    const int koff = (lane >> 4) * 8;

    short8 a[4];
#pragma unroll
    for (int ks = 0; ks < 4; ++ks)
        a[ks] = *(const short8*)&sA[l15 * LDA + ks * 32 + koff];

    f32x4 acc[2];
#pragma unroll
    for (int cb = 0; cb < 2; ++cb) acc[cb] = (f32x4){0.f, 0.f, 0.f, 0.f};
#pragma unroll
    for (int cb = 0; cb < 2; ++cb) {
        const int c = wave * 2 + cb;
        const unsigned short* wp = Wt + (size_t)(c * 16 + l15) * 128 + koff;
#pragma unroll
        for (int ks = 0; ks < 4; ++ks) {
            short8 b = *(const short8*)(wp + ks * 32);
            acc[cb] = __builtin_amdgcn_mfma_f32_16x16x32_bf16(a[ks], b, acc[cb], 0, 0, 0);
        }
    }
    const int orow = row0 + (lane >> 4) * 4;
#pragma unroll
    for (int r = 0; r < 4; ++r) {
        int gr = orow + r;
        if (gr < nN) {
            float dv = rsqrtf((float)cursorPad[gr * CPAD] + 1.0f);
#pragma unroll
            for (int cb = 0; cb < 2; ++cb)
                Y[(size_t)gr * 128 + (wave * 2 + cb) * 16 + l15] = f2bf(acc[cb][r] * dv);
        }
    }
}

// ---- fused gather2 + mean pool: SPLIT blocks per graph, gOff bounds -------------
__global__ __launch_bounds__(256) void k_gp(const uint4* __restrict__ h4in,
                                            const int* __restrict__ cursorPad,
                                            const int* __restrict__ eSrc,
                                            const float* __restrict__ bias,
                                            const int* __restrict__ gOff,
                                            float* __restrict__ out, int nN, int nG) {
    __shared__ float accW[4 * WPAD];  // 2.1 KB
    const int g = blockIdx.x / SPLIT;
    const int part = blockIdx.x % SPLIT;
    const int t = threadIdx.x;
    const int beg = gOff[g], end = gOff[g + 1];
    const int lg = t >> 4, l = t & 15;
    const int wave = t >> 6, lane = t & 63;

    float acc8[8];
#pragma unroll
    for (int j = 0; j < 8; ++j) acc8[j] = 0.0f;

    for (int base = beg + part * 16; base < end; base += SPLIT * 16) {
        int i = base + lg;
        if (i < end) {
            float a[8];
            gather_body(h4in, cursorPad, eSrc, bias, i, l, a);
#pragma unroll
            for (int j = 0; j < 8; ++j) acc8[j] += a[j];
        }
    }
#pragma unroll
    for (int j = 0; j < 8; ++j) {
        acc8[j] += __shfl_down(acc8[j], 32);
        acc8[j] += __shfl_down(acc8[j], 16);
    }
    if (lane < 16) {
        *(float4*)&accW[wave * WPAD + lane * 8] =
            make_float4(acc8[0], acc8[1], acc8[2], acc8[3]);
        *(float4*)&accW[wave * WPAD + lane * 8 + 4] =
            make_float4(acc8[4], acc8[5], acc8[6], acc8[7]);
    }
    __syncthreads();
    if (t < 128) {
        float s = accW[0 * WPAD + t] + accW[1 * WPAD + t] +
                  accW[2 * WPAD + t] + accW[3 * WPAD + t];
        float cnt = (float)(end - beg);
        atomicAdd(&out[(size_t)g * DIM + t], s / fmaxf(cnt, 1.0f));
    }
}

extern "C" void kernel_launch(void* const* d_in, const int* in_sizes, int n_in,
                              void* d_out, int out_size, void* d_ws, size_t ws_size,
                              hipStream_t stream) {
    const float* X  = (const float*)d_in[0];
    const float* W1 = (const float*)d_in[1];
    const float* b1 = (const float*)d_in[2];
    const float* W2 = (const float*)d_in[3];
    const float* b2 = (const float*)d_in[4];
    const int*   ei = (const int*)d_in[5];
    const int*   batch = (const int*)d_in[6];
    float* out = (float*)d_out;

    const int NN = in_sizes[0] / DIM;     // 50000
    const int NE = in_sizes[5] / 2;       // 600000
    const int NG = out_size / DIM;        // 1000

    const int* src = ei;
    const int* dst = ei + NE;

    char* ws = (char*)d_ws;
    size_t o = 0;
    auto alloc = [&](size_t bytes) {
        char* p = ws + o;
        o += (bytes + 1023) & ~(size_t)1023;
        return p;
    };
    int* cursorPad = (int*)alloc((size_t)NN * CPAD * 4);  // 3.2 MB
    int* gOff      = (int*)alloc((size_t)(NG + 1) * 4);
    unsigned short* Wt1 = (unsigned short*)alloc((size_t)16384 * 2);
    unsigned short* Wt2 = (unsigned short*)alloc((size_t)16384 * 2);
    int*   eSrc    = (int*)alloc((size_t)NN * ELLW * 4);                   // 12.8 MB
    unsigned short* bufA = (unsigned short*)alloc((size_t)NN * DIM * 2);   // h1' bf16
    unsigned short* bufB = (unsigned short*)alloc((size_t)NN * DIM * 2);   // h2' bf16

    hipMemsetAsync(cursorPad, 0, (size_t)NN * CPAD * 4, stream);
    hipMemsetAsync(out, 0, (size_t)out_size * 4, stream);

    const int B = 256;

    // ---- fused fill + W prep + gOff ----
    k_fillprep<<<(NE + B - 1) / B, B, 0, stream>>>(src, dst, batch, cursorPad, eSrc,
                                                   W1, W2, Wt1, Wt2, gOff, NE, NN, NG);

    // ---- layer 1 GEMM: bufA = (X @ W1) * dinv ----
    k_gemm<<<(NN + 63) / 64, B, 0, stream>>>(X, Wt1, cursorPad, bufA, NN);

    // ---- fused gather1 + GEMM2 (16-row tiles): bufB = (relu(agg(bufA)+b1) @ W2)*dinv
    k_gg<<<(NN + 15) / 16, B, 0, stream>>>((const uint4*)bufA, cursorPad, eSrc, b1,
                                           Wt2, bufB, NN);

    // ---- fused gather2 + mean pool (4 blocks/graph, gOff bounds) ----
    k_gp<<<NG * SPLIT, B, 0, stream>>>((const uint4*)bufB, cursorPad, eSrc, b2,
                                       gOff, out, NN, NG);
}